// Round 3
// baseline (1473.965 us; speedup 1.0000x reference)
//
#include <hip/hip_runtime.h>
#include <hip/hip_bf16.h>

#define B_ 32
#define H_ 56
#define W_ 56
#define C_ 128
#define NH_ 4
#define HD_ 32
#define S_ 7
#define KXW 35
#define NKEY 245
// HD^-0.5 * log2(e): scores come out pre-scaled for exp2-based softmax
#define SCL2E 0.25503486f

typedef short short8 __attribute__((ext_vector_type(8)));
typedef float f32x4 __attribute__((ext_vector_type(4)));
typedef unsigned u32x2 __attribute__((ext_vector_type(2)));

// LDS (ushort elems) -- layout identical to the verified R2 kernel.
//   K  [256][40] @ 0, V^T [32][264(+dg*40 skew)] @ 10240, P aliases K per wave.
// One block now processes all 4 heads of a window (h-loop); each head fully
// rewrites K and V^T regions, so P-dirty rows from head h-1 are benign.
#define KSTR 40
#define VSTR 264
#define PSTR 136            // 128 keys (one half) + 8 pad
#define PBLK 2176           // 16*PSTR per wave; 4 waves -> 8704 < 10240 (K region)
#define SK_OFF 0
#define SV_OFF 10240
#define SM_TOT 18960        // 37920 B -> 4 blocks/CU by LDS

__device__ __forceinline__ unsigned pk2(float a, float b) {
  __hip_bfloat162 t = __float22bfloat162_rn(float2{a, b});  // v_cvt_pk_bf16_f32
  unsigned r;
  __builtin_memcpy(&r, &t, 4);
  return r;
}
__device__ __forceinline__ float bf2f(unsigned short u) {
  unsigned x = ((unsigned)u) << 16;
  return __builtin_bit_cast(float, x);
}

__global__ __launch_bounds__(256, 4) void lepe_attn(
    const float* __restrict__ qkv, const float* __restrict__ w_lepe,
    const float* __restrict__ b_lepe, float* __restrict__ out) {
  __shared__ __align__(16) unsigned short sm[SM_TOT];

  const int n = blockIdx.x;           // grid = B*NPH*NPW = 2048; h-loop inside
  const int wx = n & 7;
  const int wy = (n >> 3) & 7;
  const int b  = n >> 6;
  const int tid  = threadIdx.x;
  const int lane = tid & 63;
  const int mt   = tid >> 6;          // wave = M-tile index
  const int quad = lane >> 4;
  const int cc   = lane & 15;

  const float* Qg = qkv;
  const float* Kg = qkv + (size_t)B_ * H_ * W_ * C_;
  const float* Vg = Kg + (size_t)B_ * H_ * W_ * C_;
  const size_t bimg = (size_t)b * H_ * W_ * C_;

  // ---- per-thread staging geometry (head-independent) ----
  const int dg = tid & 7, j0 = tid >> 3;     // 8 rows j0+32*it, fixed dim-group dg
  int rowbase[8];
  unsigned okm = 0;
#pragma unroll
  for (int it = 0; it < 8; ++it) {
    const int j = j0 + 32 * it;
    const int ky = j / KXW, kx = j - (j / KXW) * KXW;
    const int xx = wx * 7 + kx - 14;
    rowbase[it] = ((wy * 7 + ky) * W_ + xx) * C_ + dg * 4;
    if (j < NKEY && xx >= 0 && xx < W_) okm |= 1u << it;
  }
  const int mrow = mt * 16 + cc;             // query index (>=49: zero pad)
  const bool qok = mrow < 49;
  const int qy = mrow / 7, qx = mrow - (mrow / 7) * 7;
  const int qbase = ((wy * 7 + qy) * W_ + wx * 7 + qx) * C_ + quad * 8;

  unsigned kw[16], vw[16];   // converted bf16-pair words for the CURRENT head
  short8 afr;
  float4 fk[8], fv[8], fqa, fqb;
  const float4 z4 = {0.f, 0.f, 0.f, 0.f};

  // ---- prologue: load + convert head 0 ----
#pragma unroll
  for (int it = 0; it < 8; ++it) {
    fk[it] = z4; fv[it] = z4;
    if (okm >> it & 1) {
      const size_t gi = bimg + (size_t)rowbase[it];
      fk[it] = *reinterpret_cast<const float4*>(Kg + gi);
      fv[it] = *reinterpret_cast<const float4*>(Vg + gi);
    }
  }
  fqa = z4; fqb = z4;
  if (qok) {
    const float* qp = Qg + bimg + qbase;
    fqa = *reinterpret_cast<const float4*>(qp);
    fqb = *reinterpret_cast<const float4*>(qp + 4);
  }
#pragma unroll
  for (int it = 0; it < 8; ++it) {
    kw[2*it]   = pk2(fk[it].x, fk[it].y);
    kw[2*it+1] = pk2(fk[it].z, fk[it].w);
    vw[2*it]   = pk2(fv[it].x, fv[it].y);
    vw[2*it+1] = pk2(fv[it].z, fv[it].w);
  }
  {
    union { unsigned u[4]; short8 s; } au;
    au.u[0] = pk2(fqa.x * SCL2E, fqa.y * SCL2E);
    au.u[1] = pk2(fqa.z * SCL2E, fqa.w * SCL2E);
    au.u[2] = pk2(fqb.x * SCL2E, fqb.y * SCL2E);
    au.u[3] = pk2(fqb.z * SCL2E, fqb.w * SCL2E);
    afr = au.s;
  }

  for (int h = 0; h < 4; ++h) {
    const int c0 = h << 5;
    const int c1 = c0 + 32;                  // next head's dim offset

    // ---- S(h): stage converted registers to LDS (no memory wait here) ----
#pragma unroll
    for (int it = 0; it < 8; ++it) {
      const int j = j0 + 32 * it;
      *reinterpret_cast<u32x2*>(sm + SK_OFF + j * KSTR + dg * 4) =
          (u32x2){kw[2*it], kw[2*it+1]};
      unsigned short* vp = sm + SV_OFF + (dg * 4) * VSTR + dg * 40 + j;
      vp[0*VSTR] = (unsigned short)vw[2*it];
      vp[1*VSTR] = (unsigned short)(vw[2*it] >> 16);
      vp[2*VSTR] = (unsigned short)vw[2*it+1];
      vp[3*VSTR] = (unsigned short)(vw[2*it+1] >> 16);
    }
    __syncthreads();                         // B1: staged tiles visible

    // issue group A (rows it=0..3) + Q for head h+1; latency hides under QK^T
    if (h < 3) {
#pragma unroll
      for (int it = 0; it < 4; ++it) {
        fk[it] = z4; fv[it] = z4;
        if (okm >> it & 1) {
          const size_t gi = bimg + (size_t)(rowbase[it] + c1);
          fk[it] = *reinterpret_cast<const float4*>(Kg + gi);
          fv[it] = *reinterpret_cast<const float4*>(Vg + gi);
        }
      }
      fqa = z4; fqb = z4;
      if (qok) {
        const float* qp = Qg + bimg + qbase + c1;
        fqa = *reinterpret_cast<const float4*>(qp);
        fqb = *reinterpret_cast<const float4*>(qp + 4);
      }
    }

    // ---- QK^T (swapped: sim^T) + eager exp+pack (frees acc registers) ----
    // Lane (quad,cc) reg r: sim[key=nt*16+quad*4+r][q=cc]. Masks keys >= 245.
    unsigned pk[32];
    float sum = 0.f;
#pragma unroll
    for (int nt = 0; nt < 16; ++nt) {
      short8 bfr = *reinterpret_cast<const short8*>(sm + SK_OFF + (nt*16+cc)*KSTR + quad*8);
      f32x4 z = {0.f, 0.f, 0.f, 0.f};
      f32x4 a = __builtin_amdgcn_mfma_f32_16x16x32_bf16(bfr, afr, z, 0, 0, 0);
      float e0 = __builtin_amdgcn_exp2f(a[0]);
      float e1 = __builtin_amdgcn_exp2f(a[1]);
      float e2 = __builtin_amdgcn_exp2f(a[2]);
      float e3 = __builtin_amdgcn_exp2f(a[3]);
      if (nt == 15) {                        // keys 240+quad*4+r >= 245 -> 0
        e0 = (quad * 4 + 0 < 5) ? e0 : 0.f;
        e1 = (quad * 4 + 1 < 5) ? e1 : 0.f;
        e2 = (quad * 4 + 2 < 5) ? e2 : 0.f;
        e3 = (quad * 4 + 3 < 5) ? e3 : 0.f;
      }
      sum += (e0 + e1) + (e2 + e3);
      pk[2*nt]   = pk2(e0, e1);              // P left UNNORMALIZED (|e|<=~e^6, bf16-safe)
      pk[2*nt+1] = pk2(e2, e3);
    }
    sum += __shfl_xor(sum, 16, 64);
    sum += __shfl_xor(sum, 32, 64);
    const float rv = __builtin_amdgcn_rcpf(sum);   // 1/l for q = cc
    float rv4[4];                            // 1/l re-indexed to q = quad*4+r (PV rows)
#pragma unroll
    for (int r = 0; r < 4; ++r) rv4[r] = __shfl(rv, quad * 4 + r, 64);

    // convert group A + Q for head h+1 (vmcnt wait lands here, after QK^T)
    if (h < 3) {
#pragma unroll
      for (int it = 0; it < 4; ++it) {
        kw[2*it]   = pk2(fk[it].x, fk[it].y);
        kw[2*it+1] = pk2(fk[it].z, fk[it].w);
        vw[2*it]   = pk2(fv[it].x, fv[it].y);
        vw[2*it+1] = pk2(fv[it].z, fv[it].w);
      }
      union { unsigned u[4]; short8 s; } au;
      au.u[0] = pk2(fqa.x * SCL2E, fqa.y * SCL2E);
      au.u[1] = pk2(fqa.z * SCL2E, fqa.w * SCL2E);
      au.u[2] = pk2(fqb.x * SCL2E, fqb.y * SCL2E);
      au.u[3] = pk2(fqb.z * SCL2E, fqb.w * SCL2E);
      afr = au.s;                            // consumed next iteration
    }

    __syncthreads();                         // B2: K reads done -> P may alias K

    // ---- P·V in two 128-key halves; P scratch wave-private (in-wave order) ----
    unsigned short* pw = sm + SK_OFF + mt * PBLK;
    f32x4 o0 = {0.f,0.f,0.f,0.f}, o1 = {0.f,0.f,0.f,0.f};
#pragma unroll
    for (int half = 0; half < 2; ++half) {
#pragma unroll
      for (int nt = 0; nt < 8; ++nt) {
        *reinterpret_cast<u32x2*>(pw + cc * PSTR + nt * 16 + quad * 4) =
            (u32x2){pk[(half*8+nt)*2], pk[(half*8+nt)*2+1]};
      }
      if (half == 0 && h < 3) {
        // issue group B (rows it=4..7) for head h+1; hides under PV
#pragma unroll
        for (int it = 4; it < 8; ++it) {
          fk[it] = z4; fv[it] = z4;
          if (okm >> it & 1) {
            const size_t gi = bimg + (size_t)(rowbase[it] + c1);
            fk[it] = *reinterpret_cast<const float4*>(Kg + gi);
            fv[it] = *reinterpret_cast<const float4*>(Vg + gi);
          }
        }
      }
#pragma unroll
      for (int ks = 0; ks < 4; ++ks) {
        short8 pfr = *reinterpret_cast<const short8*>(pw + cc * PSTR + ks * 32 + quad * 8);
        const int keyo = half * 128 + ks * 32 + quad * 8;
        short8 v0 = *reinterpret_cast<const short8*>(
            sm + SV_OFF + cc * VSTR + (cc >> 2) * 40 + keyo);
        short8 v1 = *reinterpret_cast<const short8*>(
            sm + SV_OFF + (16 + cc) * VSTR + (4 + (cc >> 2)) * 40 + keyo);
        o0 = __builtin_amdgcn_mfma_f32_16x16x32_bf16(pfr, v0, o0, 0, 0, 0);
        o1 = __builtin_amdgcn_mfma_f32_16x16x32_bf16(pfr, v1, o1, 0, 0, 0);
      }
    }

    // convert group B for head h+1 (wait lands here, after PV)
    if (h < 3) {
#pragma unroll
      for (int it = 4; it < 8; ++it) {
        kw[2*it]   = pk2(fk[it].x, fk[it].y);
        kw[2*it+1] = pk2(fk[it].z, fk[it].w);
        vw[2*it]   = pk2(fv[it].x, fv[it].y);
        vw[2*it+1] = pk2(fv[it].z, fv[it].w);
      }
    }

    // ---- epilogue: LePE (3x3 depthwise on window center) + store ----
#pragma unroll
    for (int half = 0; half < 2; ++half) {
      const int d = cc + half * 16;
      const unsigned short* vrow = sm + SV_OFF + d * VSTR + ((d >> 2) & 7) * 40;
      float wl[9];
#pragma unroll
      for (int t = 0; t < 9; ++t) wl[t] = w_lepe[t * C_ + c0 + d];
      const float bl = b_lepe[c0 + d];
      const f32x4 o = half ? o1 : o0;
#pragma unroll
      for (int r = 0; r < 4; ++r) {
        const int p = mt * 16 + quad * 4 + r;
        if (p < 49) {
          const int y = p / 7, x = p - (p / 7) * 7;
          float l = bl;
#pragma unroll
          for (int dy = -1; dy <= 1; ++dy) {
            const int yy = y + dy;
            if (yy < 0 || yy >= 7) continue;
#pragma unroll
            for (int dx = -1; dx <= 1; ++dx) {
              const int xxp = x + dx;
              if (xxp < 0 || xxp >= 7) continue;
              const int key = yy * KXW + 14 + xxp;   // center columns kx 14..20
              l += wl[(dy + 1) * 3 + (dx + 1)] * bf2f(vrow[key]);
            }
          }
          out[bimg + ((size_t)((wy * 7 + y) * W_ + wx * 7 + x)) * C_ + c0 + d] =
              o[r] * rv4[r] + l;
        }
      }
    }
    if (h < 3) __syncthreads();              // B3: all LDS reads done -> restage safe
  }
}

extern "C" void kernel_launch(void* const* d_in, const int* in_sizes, int n_in,
                              void* d_out, int out_size, void* d_ws, size_t ws_size,
                              hipStream_t stream) {
  const float* qkv    = (const float*)d_in[0];
  const float* w_lepe = (const float*)d_in[1];
  const float* b_lepe = (const float*)d_in[2];
  float* out = (float*)d_out;
  // grid = B * NPH * NPW = 32*8*8 = 2048 blocks of 256 threads; 4 heads looped
  lepe_attn<<<2048, 256, 0, stream>>>(qkv, w_lepe, b_lepe, out);
}